// Round 7
// baseline (252.471 us; speedup 1.0000x reference)
//
#include <hip/hip_runtime.h>
#include <math.h>

#define DD 32
#define MM 16

typedef _Float16 half8 __attribute__((ext_vector_type(8)));

__device__ __forceinline__ void load8f4(const float* __restrict__ p, float* r) {
    const float4* q = (const float4*)p;
#pragma unroll
    for (int i = 0; i < 8; ++i) {
        float4 v = q[i];
        r[4*i+0] = v.x; r[4*i+1] = v.y; r[4*i+2] = v.z; r[4*i+3] = v.w;
    }
}

__device__ __forceinline__ float dot8f(const float* a, const float* b) {
    float s0 = fmaf(a[0], b[0], fmaf(a[1], b[1], 0.f));
    float s1 = fmaf(a[2], b[2], fmaf(a[3], b[3], 0.f));
    float s2 = fmaf(a[4], b[4], fmaf(a[5], b[5], 0.f));
    float s3 = fmaf(a[6], b[6], fmaf(a[7], b[7], 0.f));
    return (s0 + s1) + (s2 + s3);
}

// The ONLY prep: user_table -> fp16 (rows 128B -> 64B = 1 cache line per gather).
// Pure streaming, 19.2 MB total.  One thread per 16 elements.
__global__ void convert_user(const float* __restrict__ ut, _Float16* __restrict__ o, int n16) {
    int g = blockIdx.x * blockDim.x + threadIdx.x;
    if (g >= n16) return;
    const float4* p = (const float4*)ut + 4 * (size_t)g;
    float4 a = p[0], b = p[1], c = p[2], d = p[3];
    half8 h0, h1;
    h0[0] = (_Float16)a.x; h0[1] = (_Float16)a.y; h0[2] = (_Float16)a.z; h0[3] = (_Float16)a.w;
    h0[4] = (_Float16)b.x; h0[5] = (_Float16)b.y; h0[6] = (_Float16)b.z; h0[7] = (_Float16)b.w;
    h1[0] = (_Float16)c.x; h1[1] = (_Float16)c.y; h1[2] = (_Float16)c.z; h1[3] = (_Float16)c.w;
    h1[4] = (_Float16)d.x; h1[5] = (_Float16)d.y; h1[6] = (_Float16)d.z; h1[7] = (_Float16)d.w;
    half8* q = (half8*)o + 2 * (size_t)g;
    q[0] = h0; q[1] = h1;
}

// Quad-cooperative main with ZERO item-side precompute:
//  - lane q owns dims ko=q*8..q*8+7
//  - t[ko..ko+7] computed on the fly from the full item row (L1-broadcast) and
//    W_bil (4KB, cached): 256 FMA/lane ≈ 3-4us chip-wide — cheaper than the
//    23-45us precompute kernel it replaces, and removes a serial dispatch.
//  - member phase: len-gated pairs (R5's proven structure), fp16 quad gathers
//    (one 64B line per member row), batched shfl butterflies, fp32 accum.
//  - cj folds into the epilogue u[j] reduction via the W1[j,64+*] slice (free).
template <bool H>
__global__ __launch_bounds__(256)
void bilinear_main(const int* __restrict__ item_inputs,
                   const int* __restrict__ member_ids,
                   const unsigned char* __restrict__ member_mask,
                   const float* __restrict__ user_table,
                   const _Float16* __restrict__ ut_h,
                   const float* __restrict__ item_table,
                   const float* __restrict__ W_bil,
                   const float* __restrict__ b_bil,
                   const float* __restrict__ W1,
                   const float* __restrict__ b1v,
                   const float* __restrict__ W2,
                   const float* __restrict__ b2v,
                   float* __restrict__ out, int Btot) {
    int tid = blockIdx.x * blockDim.x + threadIdx.x;
    int b = tid >> 2;
    if (b >= Btot) return;
    int q = tid & 3;
    int ko = q * 8;

    int item = __builtin_nontemporal_load(item_inputs + b);
    const uint4 mv = *(const uint4*)(member_mask + (size_t)b * MM);
    int len = __popc(mv.x & 0x01010101u) + __popc(mv.y & 0x01010101u) +
              __popc(mv.z & 0x01010101u) + __popc(mv.w & 0x01010101u);

    // Full item row (same addr across quad -> one L1 line, broadcast).
    float itf[DD];
    load8f4(item_table + (size_t)item * DD, itf);

    // t slice on the fly: t[k] = W_bil[ko+k,:] . itf   (W_bil 4KB, cache-hot)
    float t[8];
#pragma unroll
    for (int k = 0; k < 8; ++k) {
        const float* w = W_bil + (ko + k) * DD;
        float s0 = 0.f, s1 = 0.f, s2 = 0.f, s3 = 0.f;
#pragma unroll
        for (int e = 0; e < DD; e += 4) {
            s0 = fmaf(w[e+0], itf[e+0], s0);
            s1 = fmaf(w[e+1], itf[e+1], s1);
            s2 = fmaf(w[e+2], itf[e+2], s2);
            s3 = fmaf(w[e+3], itf[e+3], s3);
        }
        t[k] = (s0 + s1) + (s2 + s3);
    }

    float bb = b_bil[0];
    float fin[8];
#pragma unroll
    for (int k = 0; k < 8; ++k) fin[k] = 0.f;

    // Len-gated member loop, pairs in flight (ids from L1-hot global, not a
    // runtime-indexed register array — rule #20).
    const int* idp = member_ids + (size_t)b * MM;
    int m = 0;
    for (; m + 2 <= len; m += 2) {
        int ida = idp[m], idb = idp[m + 1];
        float ma[8], mc[8];
        if (H) {
            half8 ha = *(const half8*)(ut_h + (size_t)ida * DD + ko);
            half8 hb = *(const half8*)(ut_h + (size_t)idb * DD + ko);
#pragma unroll
            for (int k = 0; k < 8; ++k) { ma[k] = (float)ha[k]; mc[k] = (float)hb[k]; }
        } else {
            const float4* ua = (const float4*)(user_table + (size_t)ida * DD + ko);
            const float4* ub = (const float4*)(user_table + (size_t)idb * DD + ko);
            float4 a0 = ua[0], a1 = ua[1], b0 = ub[0], b1 = ub[1];
            ma[0]=a0.x; ma[1]=a0.y; ma[2]=a0.z; ma[3]=a0.w;
            ma[4]=a1.x; ma[5]=a1.y; ma[6]=a1.z; ma[7]=a1.w;
            mc[0]=b0.x; mc[1]=b0.y; mc[2]=b0.z; mc[3]=b0.w;
            mc[4]=b1.x; mc[5]=b1.y; mc[6]=b1.z; mc[7]=b1.w;
        }
        float sa = dot8f(ma, t);
        float sb = dot8f(mc, t);
        sa += __shfl_xor(sa, 1); sb += __shfl_xor(sb, 1);
        sa += __shfl_xor(sa, 2); sb += __shfl_xor(sb, 2);
        sa += bb; sb += bb;
#pragma unroll
        for (int k = 0; k < 8; ++k)
            fin[k] = fmaf(sb, mc[k], fmaf(sa, ma[k], fin[k]));
    }
    if (m < len) {
        int ida = idp[m];
        float ma[8];
        if (H) {
            half8 ha = *(const half8*)(ut_h + (size_t)ida * DD + ko);
#pragma unroll
            for (int k = 0; k < 8; ++k) ma[k] = (float)ha[k];
        } else {
            const float4* ua = (const float4*)(user_table + (size_t)ida * DD + ko);
            float4 a0 = ua[0], a1 = ua[1];
            ma[0]=a0.x; ma[1]=a0.y; ma[2]=a0.z; ma[3]=a0.w;
            ma[4]=a1.x; ma[5]=a1.y; ma[6]=a1.z; ma[7]=a1.w;
        }
        float sa = dot8f(ma, t);
        sa += __shfl_xor(sa, 1);
        sa += __shfl_xor(sa, 2);
        sa += bb;
#pragma unroll
        for (int k = 0; k < 8; ++k) fin[k] = fmaf(sa, ma[k], fin[k]);
    }

    // it slice: separate L1-hot load (NOT itf[ko+k] — runtime index, rule #20).
    const float4* ip = (const float4*)(item_table + (size_t)item * DD + ko);
    float4 ia = ip[0], ic = ip[1];
    float it8[8] = {ia.x, ia.y, ia.z, ia.w, ic.x, ic.y, ic.z, ic.w};
    float p8[8];
#pragma unroll
    for (int k = 0; k < 8; ++k) p8[k] = fin[k] * it8[k];

    // u[j] = per-lane partial of h_j over my 8 dims across ALL THREE W1 slices
    // (f*i | f | i) — the third slice makes cj on-the-fly, no precompute.
    float u[8];
#pragma unroll
    for (int j = 0; j < 8; ++j) {
        const float* wr = W1 + j * 96 + ko;
        float4 wa0 = *(const float4*)(wr);
        float4 wa1 = *(const float4*)(wr + 4);
        float4 wb0 = *(const float4*)(wr + 32);
        float4 wb1 = *(const float4*)(wr + 36);
        float4 wc0 = *(const float4*)(wr + 64);
        float4 wc1 = *(const float4*)(wr + 68);
        float x = 0.f, y = 0.f, v = 0.f;
        x = fmaf(wa0.x, p8[0], x); y = fmaf(wb0.x, fin[0], y); v = fmaf(wc0.x, it8[0], v);
        x = fmaf(wa0.y, p8[1], x); y = fmaf(wb0.y, fin[1], y); v = fmaf(wc0.y, it8[1], v);
        x = fmaf(wa0.z, p8[2], x); y = fmaf(wb0.z, fin[2], y); v = fmaf(wc0.z, it8[2], v);
        x = fmaf(wa0.w, p8[3], x); y = fmaf(wb0.w, fin[3], y); v = fmaf(wc0.w, it8[3], v);
        x = fmaf(wa1.x, p8[4], x); y = fmaf(wb1.x, fin[4], y); v = fmaf(wc1.x, it8[4], v);
        x = fmaf(wa1.y, p8[5], x); y = fmaf(wb1.y, fin[5], y); v = fmaf(wc1.y, it8[5], v);
        x = fmaf(wa1.z, p8[6], x); y = fmaf(wb1.z, fin[6], y); v = fmaf(wc1.z, it8[6], v);
        x = fmaf(wa1.w, p8[7], x); y = fmaf(wb1.w, fin[7], y); v = fmaf(wc1.w, it8[7], v);
        u[j] = (x + y) + v;
    }
#pragma unroll
    for (int j = 0; j < 8; ++j) {
        u[j] += __shfl_xor(u[j], 1);
        u[j] += __shfl_xor(u[j], 2);
    }

    if (q == 0) {
        float z = b2v[0];
#pragma unroll
        for (int j = 0; j < 8; ++j) {
            float hv = u[j] + b1v[j];
            hv = hv > 0.f ? hv : 0.f;
            z = fmaf(W2[j], hv, z);
        }
        __builtin_nontemporal_store(1.f / (1.f + __expf(-z)), out + b);
    }
}

extern "C" void kernel_launch(void* const* d_in, const int* in_sizes, int n_in,
                              void* d_out, int out_size, void* d_ws, size_t ws_size,
                              hipStream_t stream) {
    const int*           item_inputs = (const int*)d_in[0];
    const int*           member_ids  = (const int*)d_in[1];
    const unsigned char* member_mask = (const unsigned char*)d_in[2];
    const float*         user_table  = (const float*)d_in[3];
    const float*         item_table  = (const float*)d_in[4];
    const float*         W_bil       = (const float*)d_in[5];
    const float*         b_bil       = (const float*)d_in[6];
    const float*         W1          = (const float*)d_in[7];
    const float*         b1          = (const float*)d_in[8];
    const float*         W2          = (const float*)d_in[9];
    const float*         b2          = (const float*)d_in[10];
    float* out = (float*)d_out;

    int Btot = in_sizes[0];
    int NU   = in_sizes[3] / DD;

    size_t need = (size_t)NU * DD * sizeof(_Float16);

    int blk = 256;
    long long nthreads = (long long)Btot * 4;
    if (ws_size >= need) {
        _Float16* ut_h = (_Float16*)d_ws;
        int n16 = NU * DD / 16;
        convert_user<<<(n16 + blk - 1) / blk, blk, 0, stream>>>(user_table, ut_h, n16);
        bilinear_main<true><<<(int)((nthreads + blk - 1) / blk), blk, 0, stream>>>(
            item_inputs, member_ids, member_mask, user_table, ut_h, item_table,
            W_bil, b_bil, W1, b1, W2, b2, out, Btot);
    } else {
        bilinear_main<false><<<(int)((nthreads + blk - 1) / blk), blk, 0, stream>>>(
            item_inputs, member_ids, member_mask, user_table, nullptr, item_table,
            W_bil, b_bil, W1, b1, W2, b2, out, Btot);
    }
}

// Round 8
// 170.154 us; speedup vs baseline: 1.4838x; 1.4838x over previous
//
#include <hip/hip_runtime.h>
#include <math.h>

#define DD 32
#define MM 16
#define TROW 40   // tbl row: t[32] | cj[8]  (R0-proven layout, fp32)

__device__ __forceinline__ void load8f4(const float* __restrict__ p, float* r) {
    const float4* q = (const float4*)p;
#pragma unroll
    for (int i = 0; i < 8; ++i) {
        float4 v = q[i];
        r[4*i+0] = v.x; r[4*i+1] = v.y; r[4*i+2] = v.z; r[4*i+3] = v.w;
    }
}

// 2 threads per item (half h of the row each): halves the serial FMA chain and
// doubles wave count vs R0's 1t/item, while reading the SAME 6.4 MB (the BW
// floor under the concurrent harness ws-fill is unchanged — that's the floor).
// All register-array indices compile-time (rule #20); o[] is global, runtime ok.
__global__ void precompute_item(const float* __restrict__ item_table,
                                const float* __restrict__ W_bil,
                                const float* __restrict__ W1,
                                float* __restrict__ tbl, int NI) {
    int g = blockIdx.x * blockDim.x + threadIdx.x;
    int i = g >> 1, h = g & 1;
    if (i >= NI) return;
    float it[DD];
    load8f4(item_table + (size_t)i * DD, it);   // 2 lanes same addr -> broadcast
    float* o = tbl + (size_t)i * TROW;
    int d0 = h * 16;
#pragma unroll
    for (int k = 0; k < 16; ++k) {
        const float* w = W_bil + (d0 + k) * DD;
        float s0 = 0.f, s1 = 0.f, s2 = 0.f, s3 = 0.f;
#pragma unroll
        for (int e = 0; e < DD; e += 4) {
            s0 = fmaf(w[e+0], it[e+0], s0);
            s1 = fmaf(w[e+1], it[e+1], s1);
            s2 = fmaf(w[e+2], it[e+2], s2);
            s3 = fmaf(w[e+3], it[e+3], s3);
        }
        o[d0 + k] = (s0 + s1) + (s2 + s3);
    }
#pragma unroll
    for (int jj = 0; jj < 4; ++jj) {
        int j = h * 4 + jj;
        const float* w1 = W1 + j * 96 + 64;
        float c0 = 0.f, c1 = 0.f, c2 = 0.f, c3 = 0.f;
#pragma unroll
        for (int e = 0; e < DD; e += 4) {
            c0 = fmaf(w1[e+0], it[e+0], c0);
            c1 = fmaf(w1[e+1], it[e+1], c1);
            c2 = fmaf(w1[e+2], it[e+2], c2);
            c3 = fmaf(w1[e+3], it[e+3], c3);
        }
        o[32 + j] = (c0 + c1) + (c2 + c3);
    }
}

__device__ __forceinline__ float dot32(const float* __restrict__ a,
                                       const float* __restrict__ t) {
    float s0 = 0.f, s1 = 0.f, s2 = 0.f, s3 = 0.f;
#pragma unroll
    for (int d = 0; d < DD; d += 4) {
        s0 = fmaf(a[d+0], t[d+0], s0);
        s1 = fmaf(a[d+1], t[d+1], s1);
        s2 = fmaf(a[d+2], t[d+2], s2);
        s3 = fmaf(a[d+3], t[d+3], s3);
    }
    return (s0 + s1) + (s2 + s3);
}

// R0's proven 1-thread-per-b main with two rule-#20 / pipelining fixes:
//  - member ids read straight from global (L1-hot) — R0's ids[m] runtime index
//    put the 64B array in scratch, a dependent scratch load per iteration.
//  - depth-1 software pipeline with statically-named buffers A/B: next row's
//    8 float4 loads are issued while the current row's 72-op dot/accumulate
//    runs, halving the per-member serial latency chain. Len-gated, so gather
//    traffic is unchanged (the R3/R6 mistake was un-gating it).
template <bool USE_TBL>
__global__ __launch_bounds__(256)
void bilinear_main(const int* __restrict__ item_inputs,
                   const int* __restrict__ member_ids,
                   const unsigned char* __restrict__ member_mask,
                   const float* __restrict__ user_table,
                   const float* __restrict__ item_table,
                   const float* __restrict__ tbl,
                   const float* __restrict__ W_bil,
                   const float* __restrict__ b_bil,
                   const float* __restrict__ W1,
                   const float* __restrict__ b1v,
                   const float* __restrict__ W2,
                   const float* __restrict__ b2v,
                   float* __restrict__ out, int Btot) {
    int b = blockIdx.x * blockDim.x + threadIdx.x;
    if (b >= Btot) return;

    int item = item_inputs[b];

    uint4 mv = *(const uint4*)(member_mask + (size_t)b * MM);
    int len = __popc(mv.x & 0x01010101u) + __popc(mv.y & 0x01010101u) +
              __popc(mv.z & 0x01010101u) + __popc(mv.w & 0x01010101u);

    const int* idp = member_ids + (size_t)b * MM;

    float t[DD];
    float cj[8];
    const float* tb = nullptr;
    if (USE_TBL) {
        tb = tbl + (size_t)item * TROW;
        load8f4(tb, t);
        float4 c0 = *(const float4*)(tb + 32);
        float4 c1 = *(const float4*)(tb + 36);
        cj[0] = c0.x; cj[1] = c0.y; cj[2] = c0.z; cj[3] = c0.w;
        cj[4] = c1.x; cj[5] = c1.y; cj[6] = c1.z; cj[7] = c1.w;
    } else {
        float it0[DD];
        load8f4(item_table + (size_t)item * DD, it0);
#pragma unroll 4
        for (int d = 0; d < DD; ++d) {
            float s = 0.f;
#pragma unroll
            for (int e = 0; e < DD; ++e) s = fmaf(W_bil[d * DD + e], it0[e], s);
            t[d] = s;
        }
#pragma unroll
        for (int j = 0; j < 8; ++j) {
            float s = 0.f;
#pragma unroll
            for (int d = 0; d < DD; ++d) s = fmaf(W1[j * 96 + 64 + d], it0[d], s);
            cj[j] = s;
        }
    }

    float bb = b_bil[0];
    float fin[DD];
#pragma unroll
    for (int d = 0; d < DD; ++d) fin[d] = 0.f;

    // Depth-1 pipelined member loop (static A/B buffer names, len-gated).
    float A[DD], Bv[DD];
    load8f4(user_table + (size_t)idp[0] * DD, A);   // len >= 1 always
    int m = 0;
    while (m < len) {
        if (m + 1 < len) load8f4(user_table + (size_t)idp[m + 1] * DD, Bv);
        {
            float s = dot32(A, t) + bb;
#pragma unroll
            for (int d = 0; d < DD; ++d) fin[d] = fmaf(s, A[d], fin[d]);
        }
        ++m;
        if (m >= len) break;
        if (m + 1 < len) load8f4(user_table + (size_t)idp[m + 1] * DD, A);
        {
            float s = dot32(Bv, t) + bb;
#pragma unroll
            for (int d = 0; d < DD; ++d) fin[d] = fmaf(s, Bv[d], fin[d]);
        }
        ++m;
    }

    float it[DD];
    load8f4(item_table + (size_t)item * DD, it);

    // MLP: h_j = relu(cj_j + b1_j + sum_d W1[j,d]*(f*i)[d] + W1[j,32+d]*f[d])
    float h[8];
#pragma unroll
    for (int j = 0; j < 8; ++j) h[j] = cj[j] + b1v[j];
#pragma unroll
    for (int d = 0; d < DD; ++d) {
        float f = fin[d];
        float p = f * it[d];
#pragma unroll
        for (int j = 0; j < 8; ++j) {
            h[j] = fmaf(W1[j * 96 + d], p, h[j]);
            h[j] = fmaf(W1[j * 96 + 32 + d], f, h[j]);
        }
    }
    float z = b2v[0];
#pragma unroll
    for (int j = 0; j < 8; ++j) {
        float hv = h[j] > 0.f ? h[j] : 0.f;
        z = fmaf(W2[j], hv, z);
    }
    out[b] = 1.f / (1.f + __expf(-z));
}

extern "C" void kernel_launch(void* const* d_in, const int* in_sizes, int n_in,
                              void* d_out, int out_size, void* d_ws, size_t ws_size,
                              hipStream_t stream) {
    const int*           item_inputs = (const int*)d_in[0];
    const int*           member_ids  = (const int*)d_in[1];
    const unsigned char* member_mask = (const unsigned char*)d_in[2];
    const float*         user_table  = (const float*)d_in[3];
    const float*         item_table  = (const float*)d_in[4];
    const float*         W_bil       = (const float*)d_in[5];
    const float*         b_bil       = (const float*)d_in[6];
    const float*         W1          = (const float*)d_in[7];
    const float*         b1          = (const float*)d_in[8];
    const float*         W2          = (const float*)d_in[9];
    const float*         b2          = (const float*)d_in[10];
    float* out = (float*)d_out;

    int Btot = in_sizes[0];
    int NI   = in_sizes[4] / DD;

    bool use_tbl = ws_size >= (size_t)NI * TROW * sizeof(float);
    int blk = 256;
    if (use_tbl) {
        float* tbl = (float*)d_ws;
        precompute_item<<<(NI * 2 + blk - 1) / blk, blk, 0, stream>>>(item_table, W_bil, W1, tbl, NI);
        bilinear_main<true><<<(Btot + blk - 1) / blk, blk, 0, stream>>>(
            item_inputs, member_ids, member_mask, user_table, item_table, tbl,
            W_bil, b_bil, W1, b1, W2, b2, out, Btot);
    } else {
        bilinear_main<false><<<(Btot + blk - 1) / blk, blk, 0, stream>>>(
            item_inputs, member_ids, member_mask, user_table, item_table, nullptr,
            W_bil, b_bil, W1, b1, W2, b2, out, Btot);
    }
}